// Round 6
// baseline (2834.742 us; speedup 1.0000x reference)
//
#include <hip/hip_runtime.h>

typedef float4 f4;

// ---- ws float-offset layout ----
#define F_S0   0        // 64: per-row W0 scales
#define F_BN0  64       // g[64] be[64] m[64] r[64]
#define F_BN1  320
#define F_BN2  576
#define F_BN3  832      // g[16] be[16] m[16] r[16]
#define F_WQ1  896      // 4096 fp32 [64][64]
#define F_WQ2  4992     // 4096 fp32
#define F_WQ3  9088     // 640 fp32 [10][64]
#define F_WI8  9728     // int8 tiled W0: 196608 B
#define F_WQ0  58880    // fp32 tiled W0: 196608 floats (optional)
#define WS_NEED_F32 ((size_t)(F_WQ0 + 196608) * 4)

struct InPtrs { const float* p[25]; };

// ---------------- prep: fp32 scales/weights/BN consts (np-f32 exact ops) ----------------
__global__ __launch_bounds__(256) void qtfc_prep(InPtrs P, float* __restrict__ wsf, int wf32) {
#pragma clang fp contract(off)
  __shared__ float red[256];
  const int tid = threadIdx.x, b = blockIdx.x;
  if (b < 64) {
    const int row = b;
    const float* W = P.p[1];
    float mx = 0.f;
    for (int k = tid; k < 3072; k += 256) mx = fmaxf(mx, fabsf(W[row * 3072 + k]));
    red[tid] = mx; __syncthreads();
    for (int s = 128; s > 0; s >>= 1) { if (tid < s) red[tid] = fmaxf(red[tid], red[tid + s]); __syncthreads(); }
    const float sv = fmaxf(__fdiv_rn(red[0], 7.f), 1e-8f);
    const int g = row >> 3, jj = row & 7;
    signed char* wi8 = (signed char*)(wsf + F_WI8);
    float* wq0 = wsf + F_WQ0;
    for (int k = tid; k < 3072; k += 256) {
      const float r = rintf(__fdiv_rn(W[row * 3072 + k], sv));
      const int idx = (((g * 96 + (k >> 5)) * 8 + ((k >> 2) & 7)) * 32) + jj * 4 + (k & 3);
      wi8[idx] = (signed char)(int)r;
      if (wf32) wq0[idx] = __fmul_rn(r, sv);
    }
    if (tid == 0) {
      wsf[F_S0 + row] = sv;
      const float gg = P.p[3][row], be = P.p[4][row], m = P.p[5][row], v = P.p[6][row];
      const float rr = __fdiv_rn(1.f, __fsqrt_rn(__fadd_rn(v, 1e-5f)));
      wsf[F_BN0 + row] = gg; wsf[F_BN0 + 64 + row] = be; wsf[F_BN0 + 128 + row] = m; wsf[F_BN0 + 192 + row] = rr;
    }
  } else if (b < 192) {
    const int lay = b >> 6, row = b & 63;   // lay = 1,2
    const float* W = P.p[1 + 6 * lay];
    red[tid] = (tid < 64) ? fabsf(W[row * 64 + tid]) : 0.f; __syncthreads();
    for (int s = 128; s > 0; s >>= 1) { if (tid < s) red[tid] = fmaxf(red[tid], red[tid + s]); __syncthreads(); }
    const float sv = fmaxf(__fdiv_rn(red[0], 7.f), 1e-8f);
    float* wq = wsf + (lay == 1 ? F_WQ1 : F_WQ2);
    if (tid < 64)
      wq[row * 64 + tid] = __fmul_rn(rintf(__fdiv_rn(W[row * 64 + tid], sv)), sv);
    if (tid == 0) {
      const int base = (lay == 1) ? F_BN1 : F_BN2;
      const float gg = P.p[3 + 6 * lay][row], be = P.p[4 + 6 * lay][row];
      const float m = P.p[5 + 6 * lay][row], v = P.p[6 + 6 * lay][row];
      const float rr = __fdiv_rn(1.f, __fsqrt_rn(__fadd_rn(v, 1e-5f)));
      wsf[base + row] = gg; wsf[base + 64 + row] = be; wsf[base + 128 + row] = m; wsf[base + 192 + row] = rr;
    }
  } else {
    const float* W = P.p[19];
    float mx = 0.f;
    for (int k = tid; k < 640; k += 256) mx = fmaxf(mx, fabsf(W[k]));
    red[tid] = mx; __syncthreads();
    for (int s = 128; s > 0; s >>= 1) { if (tid < s) red[tid] = fmaxf(red[tid], red[tid + s]); __syncthreads(); }
    const float sv = fmaxf(__fdiv_rn(red[0], 7.f), 1e-8f);
    for (int k = tid; k < 640; k += 256)
      wsf[F_WQ3 + k] = __fmul_rn(rintf(__fdiv_rn(W[k], sv)), sv);
    if (tid < 10) {
      const float gg = P.p[21][tid], be = P.p[22][tid], m = P.p[23][tid], v = P.p[24][tid];
      const float rr = __fdiv_rn(1.f, __fsqrt_rn(__fadd_rn(v, 1e-5f)));
      wsf[F_BN3 + tid] = gg; wsf[F_BN3 + 16 + tid] = be; wsf[F_BN3 + 32 + tid] = m; wsf[F_BN3 + 48 + tid] = rr;
    }
  }
}

// ---------------- exact-np helpers ----------------
__device__ __forceinline__ float bn_act4(float hv, float g, float be, float m, float r) {
#pragma clang fp contract(off)
  const float bnv = __fadd_rn(__fmul_rn(__fmul_rn(g, __fsub_rn(hv, m)), r), be);
  const float y = fminf(fmaxf(bnv, -1.f), 1.f);
  return __fdiv_rn(rintf(__fmul_rn(y, 7.f)), 7.f);
}
__device__ __forceinline__ float lutq(float v, const float* lut) {
#pragma clang fp contract(off)
  const float y = fminf(fmaxf(v, -1.f), 1.f);
  const float r = rintf(__fmul_rn(y, 127.f));
  return lut[(int)r + 127];   // == __fdiv_rn(r, 127.f), precomputed
}

// lean 8-row x 64-ch FC layer: 1 row/lane, 8 ch/lane, direct LDS reads (no reg arrays)
__device__ __forceinline__ void layer64lean(const f4* src, f4* dst,
                                            const f4* __restrict__ wq4,
                                            const float* __restrict__ bn,
                                            int rq, int cq) {
#pragma clang fp contract(off)
  float af[8];
#pragma unroll
  for (int j = 0; j < 8; ++j) {
    const int ch = 8 * cq + j;
    float a = 0.f;
#pragma unroll 4
    for (int s = 0; s < 16; ++s) {
      const f4 av = src[rq * 16 + (((s & 7) ^ rq) | (s & 8))];
      const f4 wv = wq4[ch * 16 + s];
      a = __fmaf_rn(av.x, wv.x, a);
      a = __fmaf_rn(av.y, wv.y, a);
      a = __fmaf_rn(av.z, wv.z, a);
      a = __fmaf_rn(av.w, wv.w, a);
    }
    af[j] = bn_act4(a, bn[ch], bn[64 + ch], bn[128 + ch], bn[192 + ch]);
  }
#pragma unroll
  for (int e = 0; e < 2; ++e) {
    const int lq = 2 * cq + e;
    const int pq = ((lq & 7) ^ rq) | (lq & 8);
    f4 v; v.x = af[4 * e]; v.y = af[4 * e + 1]; v.z = af[4 * e + 2]; v.w = af[4 * e + 3];
    dst[rq * 16 + pq] = v;
  }
}

// ---------------- main: 128 thr (2 waves), 1 row/lane, wave-private, no barriers ----------------
template<int W8>
__global__ __launch_bounds__(128) void qtfc_main(const float* __restrict__ x,
                                                 const float* __restrict__ wsf,
                                                 float* __restrict__ out) {
#pragma clang fp contract(off)
  __shared__ __align__(16) float smem[2][1280];  // per wave: a1=[0:512) (xt=[0:256)) | a2=[512:1024) | lut=[1024:1280)
  const int tid = threadIdx.x;
  const int w = tid >> 6, l = tid & 63;
  const int rq = l >> 3, cq = l & 7;
  const int row0 = blockIdx.x * 16 + w * 8;
  float* R = smem[w];
  f4* xt4 = (f4*)R;
  f4* a14 = (f4*)R;
  f4* a24 = (f4*)(R + 512);
  float* lut = R + 1024;

  // per-wave LUT: lut[r+127] = fdiv_rn(r,127)
#pragma unroll
  for (int ii = 0; ii < 4; ++ii) {
    const int idx = ii * 64 + l;
    lut[idx] = __fdiv_rn((float)(idx - 127), 127.f);
  }

  float svj[8];
  if (W8) {
#pragma unroll
    for (int j = 0; j < 8; ++j) svj[j] = wsf[F_S0 + 8 * cq + j];
  }

  // x staging: lane stages one f4 of its own row per tile; slot XOR-swizzled
  const float* xb = x + (long)(row0 + rq) * 3072 + cq * 4;
  f4 gx = *(const f4*)xb;
  const int stq = rq * 8 + (cq ^ rq);

  float acc[8], hs[8];
#pragma unroll
  for (int j = 0; j < 8; ++j) { acc[j] = 0.f; hs[j] = 0.f; }

  const f4* wg = (const f4*)(wsf + F_WQ0) + (long)cq * 96 * 64;     // per tile: 64 f4 (8s x 8j)
  const int4* w8g = (const int4*)(wsf + F_WI8) + (long)cq * 96 * 16;

#pragma unroll 1
  for (int t = 0; t < 96; ++t) {
    // quantize + stage this lane's f4 (wave-private LDS, in-wave ordered)
    {
      f4 q;
      q.x = lutq(gx.x, lut); q.y = lutq(gx.y, lut);
      q.z = lutq(gx.z, lut); q.w = lutq(gx.w, lut);
      xt4[stq] = q;
    }
    const int tn = (t < 95) ? t + 1 : 95;
    gx = *(const f4*)(xb + tn * 32);

    if (!W8) {
      const f4* wt = wg + t * 64;
#pragma unroll 1
      for (int s = 0; s < 8; ++s) {
        const f4 xa = xt4[rq * 8 + (s ^ rq)];
        const f4* wts = wt + s * 8;
#pragma unroll
        for (int jh = 0; jh < 2; ++jh) {
          const f4 w0 = wts[jh * 4 + 0];
          const f4 w1 = wts[jh * 4 + 1];
          const f4 w2 = wts[jh * 4 + 2];
          const f4 w3 = wts[jh * 4 + 3];
          float a0 = acc[jh * 4 + 0], a1 = acc[jh * 4 + 1];
          float a2 = acc[jh * 4 + 2], a3 = acc[jh * 4 + 3];
          a0 = __fmaf_rn(xa.x, w0.x, a0); a0 = __fmaf_rn(xa.y, w0.y, a0);
          a0 = __fmaf_rn(xa.z, w0.z, a0); a0 = __fmaf_rn(xa.w, w0.w, a0);
          a1 = __fmaf_rn(xa.x, w1.x, a1); a1 = __fmaf_rn(xa.y, w1.y, a1);
          a1 = __fmaf_rn(xa.z, w1.z, a1); a1 = __fmaf_rn(xa.w, w1.w, a1);
          a2 = __fmaf_rn(xa.x, w2.x, a2); a2 = __fmaf_rn(xa.y, w2.y, a2);
          a2 = __fmaf_rn(xa.z, w2.z, a2); a2 = __fmaf_rn(xa.w, w2.w, a2);
          a3 = __fmaf_rn(xa.x, w3.x, a3); a3 = __fmaf_rn(xa.y, w3.y, a3);
          a3 = __fmaf_rn(xa.z, w3.z, a3); a3 = __fmaf_rn(xa.w, w3.w, a3);
          acc[jh * 4 + 0] = a0; acc[jh * 4 + 1] = a1;
          acc[jh * 4 + 2] = a2; acc[jh * 4 + 3] = a3;
        }
      }
    } else {
      const int4* wt = w8g + t * 16;
#pragma unroll 1
      for (int s = 0; s < 8; ++s) {
        const f4 xa = xt4[rq * 8 + (s ^ rq)];
        const int4 da = wt[s * 2], db = wt[s * 2 + 1];
        const int wd[8] = {da.x, da.y, da.z, da.w, db.x, db.y, db.z, db.w};
#pragma unroll
        for (int j = 0; j < 8; ++j) {
          const int d = wd[j];
          float a = acc[j];
          a = __fmaf_rn(xa.x, __fmul_rn((float)((signed char)(d & 255)), svj[j]), a);
          a = __fmaf_rn(xa.y, __fmul_rn((float)((signed char)((d >> 8) & 255)), svj[j]), a);
          a = __fmaf_rn(xa.z, __fmul_rn((float)((signed char)((d >> 16) & 255)), svj[j]), a);
          a = __fmaf_rn(xa.w, __fmul_rn((float)((signed char)((d >> 24) & 255)), svj[j]), a);
          acc[j] = a;
        }
      }
    }

    if ((t % 12) == 11) {   // end of KC=384 block: sequential fp32 block-sum combine
#pragma unroll
      for (int j = 0; j < 8; ++j) { hs[j] = __fadd_rn(hs[j], acc[j]); acc[j] = 0.f; }
    }
  }

  // ---- layer-0 epilogue: BN + 4-bit act -> a1 ----
  {
    const float* bn0 = wsf + F_BN0;
    float af[8];
#pragma unroll
    for (int j = 0; j < 8; ++j) {
      const int ch = 8 * cq + j;
      af[j] = bn_act4(hs[j], bn0[ch], bn0[64 + ch], bn0[128 + ch], bn0[192 + ch]);
    }
#pragma unroll
    for (int e = 0; e < 2; ++e) {
      const int lq = 2 * cq + e;
      const int pq = ((lq & 7) ^ rq) | (lq & 8);
      f4 v; v.x = af[4 * e]; v.y = af[4 * e + 1]; v.z = af[4 * e + 2]; v.w = af[4 * e + 3];
      a14[rq * 16 + pq] = v;
    }
  }

  // ---- layers 1,2 ----
  layer64lean(a14, a24, (const f4*)(wsf + F_WQ1), wsf + F_BN1, rq, cq);
  layer64lean(a24, a14, (const f4*)(wsf + F_WQ2), wsf + F_BN2, rq, cq);

  // ---- layer 3: 10 outputs, BN, no act ----
  {
    const f4* wq3 = (const f4*)(wsf + F_WQ3);
    const float* bn3 = wsf + F_BN3;
#pragma unroll
    for (int j = 0; j < 8; ++j) {
      const int ch = 8 * cq + j;
      if (ch < 10) {
        float a = 0.f;
#pragma unroll 4
        for (int s = 0; s < 16; ++s) {
          const f4 av = a14[rq * 16 + (((s & 7) ^ rq) | (s & 8))];
          const f4 wv = wq3[ch * 16 + s];
          a = __fmaf_rn(av.x, wv.x, a);
          a = __fmaf_rn(av.y, wv.y, a);
          a = __fmaf_rn(av.z, wv.z, a);
          a = __fmaf_rn(av.w, wv.w, a);
        }
        const float o = __fadd_rn(__fmul_rn(__fmul_rn(bn3[ch], __fsub_rn(a, bn3[32 + ch])), bn3[48 + ch]), bn3[16 + ch]);
        out[(long)(row0 + rq) * 10 + ch] = o;
      }
    }
  }
}

extern "C" void kernel_launch(void* const* d_in, const int* in_sizes, int n_in,
                              void* d_out, int out_size, void* d_ws, size_t ws_size,
                              hipStream_t stream) {
  (void)in_sizes; (void)n_in; (void)out_size;
  InPtrs P;
  for (int i = 0; i < 25; ++i) P.p[i] = (const float*)d_in[i];
  float* wsf = (float*)d_ws;
  const int wf32 = (ws_size >= WS_NEED_F32) ? 1 : 0;
  qtfc_prep<<<193, 256, 0, stream>>>(P, wsf, wf32);
  if (wf32)
    qtfc_main<0><<<2048, 128, 0, stream>>>((const float*)d_in[0], wsf, (float*)d_out);
  else
    qtfc_main<1><<<2048, 128, 0, stream>>>((const float*)d_in[0], wsf, (float*)d_out);
}

// Round 7
// 364.992 us; speedup vs baseline: 7.7666x; 7.7666x over previous
//
#include <hip/hip_runtime.h>

typedef float4 f4;

// ---- ws float-offset layout ----
#define F_S0    0        // 64: per-channel W0 scale
#define F_BN0   64       // g[64] be[64] m[64] r[64]
#define F_BN1   320
#define F_BN2   576
#define F_BN3   832      // 256 floats (c<10 valid, rest 0)
#define F_WQ1   1088     // [16][64][4] fp32
#define F_WQ2   5184     // [16][64][4]
#define F_WQ3   9280     // [16][64][4] (zeros for c>=10)
#define F_WI0   13376    // int8 W0 tiled [768][64][4] = 196608 B
#define F_WQ0   62528    // fp32 W0 tiled [768][64][4] = 196608 floats
#define WS_NEED_F32 ((size_t)(F_WQ0 + 196608) * 4)

struct InPtrs { const float* p[25]; };

// ---------------- prep: fp32 scales/weights/BN consts (np-f32 exact ops) ----------------
__global__ __launch_bounds__(256) void qtfc_prep(InPtrs P, float* __restrict__ wsf, int wf32) {
#pragma clang fp contract(off)
  __shared__ float red[256];
  const int tid = threadIdx.x, b = blockIdx.x;
  if (b < 64) {
    const int c = b;                       // output channel
    const float* W = P.p[1];
    float mx = 0.f;
    for (int k = tid; k < 3072; k += 256) mx = fmaxf(mx, fabsf(W[c * 3072 + k]));
    red[tid] = mx; __syncthreads();
    for (int s = 128; s > 0; s >>= 1) { if (tid < s) red[tid] = fmaxf(red[tid], red[tid + s]); __syncthreads(); }
    const float sv = fmaxf(__fdiv_rn(red[0], 7.f), 1e-8f);
    signed char* wi = (signed char*)(wsf + F_WI0);
    for (int k = tid; k < 3072; k += 256) {
      const float r = rintf(__fdiv_rn(W[c * 3072 + k], sv));
      const int idx = (k >> 2) * 256 + c * 4 + (k & 3);   // [chunk][lane=c][4]
      wi[idx] = (signed char)(int)r;
      if (wf32) wsf[F_WQ0 + idx] = __fmul_rn(r, sv);
    }
    if (tid == 0) {
      wsf[F_S0 + c] = sv;
      const float gg = P.p[3][c], be = P.p[4][c], m = P.p[5][c], v = P.p[6][c];
      const float rr = __fdiv_rn(1.f, __fsqrt_rn(__fadd_rn(v, 1e-5f)));
      wsf[F_BN0 + c] = gg; wsf[F_BN0 + 64 + c] = be; wsf[F_BN0 + 128 + c] = m; wsf[F_BN0 + 192 + c] = rr;
    }
  } else if (b < 192) {
    const int lay = b >> 6, c = b & 63;    // lay = 1,2
    const float* W = P.p[1 + 6 * lay];
    red[tid] = (tid < 64) ? fabsf(W[c * 64 + tid]) : 0.f; __syncthreads();
    for (int s = 128; s > 0; s >>= 1) { if (tid < s) red[tid] = fmaxf(red[tid], red[tid + s]); __syncthreads(); }
    const float sv = fmaxf(__fdiv_rn(red[0], 7.f), 1e-8f);
    float* wq = wsf + (lay == 1 ? F_WQ1 : F_WQ2);
    if (tid < 64) {
      const int k = tid;
      wq[(k >> 2) * 256 + c * 4 + (k & 3)] = __fmul_rn(rintf(__fdiv_rn(W[c * 64 + k], sv)), sv);
    }
    if (tid == 0) {
      const int base = (lay == 1) ? F_BN1 : F_BN2;
      const float gg = P.p[3 + 6 * lay][c], be = P.p[4 + 6 * lay][c];
      const float m = P.p[5 + 6 * lay][c], v = P.p[6 + 6 * lay][c];
      const float rr = __fdiv_rn(1.f, __fsqrt_rn(__fadd_rn(v, 1e-5f)));
      wsf[base + c] = gg; wsf[base + 64 + c] = be; wsf[base + 128 + c] = m; wsf[base + 192 + c] = rr;
    }
  } else {
    // W3: zero-pad then per-tensor quant over 10x64
    for (int i = tid; i < 4096; i += 256) wsf[F_WQ3 + i] = 0.f;
    for (int i = tid; i < 256; i += 256) wsf[F_BN3 + i] = 0.f;
    __syncthreads();
    const float* W = P.p[19];
    float mx = 0.f;
    for (int k = tid; k < 640; k += 256) mx = fmaxf(mx, fabsf(W[k]));
    red[tid] = mx; __syncthreads();
    for (int s = 128; s > 0; s >>= 1) { if (tid < s) red[tid] = fmaxf(red[tid], red[tid + s]); __syncthreads(); }
    const float sv = fmaxf(__fdiv_rn(red[0], 7.f), 1e-8f);
    for (int i = tid; i < 640; i += 256) {
      const int c = i >> 6, k = i & 63;
      wsf[F_WQ3 + (k >> 2) * 256 + c * 4 + (k & 3)] = __fmul_rn(rintf(__fdiv_rn(W[i], sv)), sv);
    }
    if (tid < 10) {
      const float gg = P.p[21][tid], be = P.p[22][tid], m = P.p[23][tid], v = P.p[24][tid];
      const float rr = __fdiv_rn(1.f, __fsqrt_rn(__fadd_rn(v, 1e-5f)));
      wsf[F_BN3 + tid] = gg; wsf[F_BN3 + 16 + tid] = be; wsf[F_BN3 + 32 + tid] = m; wsf[F_BN3 + 48 + tid] = rr;
    }
  }
}

// ---------------- exact-np helpers ----------------
__device__ __forceinline__ float bn_act4(float hv, float g, float be, float m, float r) {
#pragma clang fp contract(off)
  const float bnv = __fadd_rn(__fmul_rn(__fmul_rn(g, __fsub_rn(hv, m)), r), be);
  const float y = fminf(fmaxf(bnv, -1.f), 1.f);
  return __fdiv_rn(rintf(__fmul_rn(y, 7.f)), 7.f);
}
__device__ __forceinline__ float lutq(float v, const float* lut) {
#pragma clang fp contract(off)
  const float y = fminf(fmaxf(v, -1.f), 1.f);
  const float r = rintf(__fmul_rn(y, 127.f));
  return lut[(int)r + 127];   // == __fdiv_rn(r, 127.f)
}
__device__ __forceinline__ f4 q4(f4 v, const float* lut) {
  f4 q; q.x = lutq(v.x, lut); q.y = lutq(v.y, lut); q.z = lutq(v.z, lut); q.w = lutq(v.w, lut);
  return q;
}
__device__ __forceinline__ f4 dec8(int d, float sv) {
#pragma clang fp contract(off)
  f4 w;
  w.x = __fmul_rn((float)((signed char)(d & 255)), sv);
  w.y = __fmul_rn((float)((signed char)((d >> 8) & 255)), sv);
  w.z = __fmul_rn((float)((signed char)((d >> 16) & 255)), sv);
  w.w = __fmul_rn((float)((signed char)((d >> 24) & 255)), sv);
  return w;
}

// ---------------- main: lane = channel, wave = 16 rows, wave-private, no barriers ----------------
template<int W8>
__global__ __launch_bounds__(256) void qtfc_main(const float* __restrict__ x,
                                                 const float* __restrict__ wsf,
                                                 float* __restrict__ out) {
#pragma clang fp contract(off)
  __shared__ __align__(16) float smem[4][2304];  // per wave: xt/a1 [0:1024) | a2 [1024:2048) | lut [2048:2304)
  const int tid = threadIdx.x, w = tid >> 6, l = tid & 63;
  float* R = smem[w];
  float* xa1 = R;                 // x-tile (16x16 f4) during L0; a1 [16][64] f32 after
  float* a2  = R + 1024;
  float* lut = R + 2048;
  const int row0 = blockIdx.x * 64 + w * 16;

#pragma unroll
  for (int ii = 0; ii < 4; ++ii) {
    const int idx = ii * 64 + l;
    lut[idx] = __fdiv_rn((float)(idx - 127), 127.f);
  }

  float svc = 0.f;
  if (W8) svc = wsf[F_S0 + l];

  // x staging: lane covers row = l&15, k-slots (l>>4)+4i within 64-k tile
  const int rowl = l & 15, sb = l >> 4, key = rowl & 7;
  const float* xb = x + (long)(row0 + rowl) * 3072 + sb * 4;
  f4 gx0 = *(const f4*)(xb);
  f4 gx1 = *(const f4*)(xb + 16);
  f4 gx2 = *(const f4*)(xb + 32);
  f4 gx3 = *(const f4*)(xb + 48);
  const int stw0 = rowl * 16 + ((sb) ^ key);
  const int stw1 = rowl * 16 + ((sb + 4) ^ key);
  const int stw2 = rowl * 16 + ((sb + 8) ^ key);
  const int stw3 = rowl * 16 + ((sb + 12) ^ key);

  float acc[16], hs[16];
#pragma unroll
  for (int r = 0; r < 16; ++r) { acc[r] = 0.f; hs[r] = 0.f; }

  const f4* wq0 = (const f4*)(wsf + F_WQ0);
  const int* wi0 = (const int*)(wsf + F_WI0);
  f4* xt4 = (f4*)xa1;

#pragma unroll 1
  for (int t = 0; t < 48; ++t) {
    // quantize + stage tile t (wave-private)
    xt4[stw0] = q4(gx0, lut);
    xt4[stw1] = q4(gx1, lut);
    xt4[stw2] = q4(gx2, lut);
    xt4[stw3] = q4(gx3, lut);
    // prefetch tile t+1 x
    const int tn = (t < 47) ? t + 1 : 47;
    gx0 = *(const f4*)(xb + tn * 64);
    gx1 = *(const f4*)(xb + tn * 64 + 16);
    gx2 = *(const f4*)(xb + tn * 64 + 32);
    gx3 = *(const f4*)(xb + tn * 64 + 48);

#pragma unroll
    for (int qq = 0; qq < 4; ++qq) {
      const int g0 = t * 16 + qq * 4;
      f4 wv0, wv1, wv2, wv3;
      if (!W8) {
        wv0 = wq0[(g0 + 0) * 64 + l];
        wv1 = wq0[(g0 + 1) * 64 + l];
        wv2 = wq0[(g0 + 2) * 64 + l];
        wv3 = wq0[(g0 + 3) * 64 + l];
      } else {
        wv0 = dec8(wi0[(g0 + 0) * 64 + l], svc);
        wv1 = dec8(wi0[(g0 + 1) * 64 + l], svc);
        wv2 = dec8(wi0[(g0 + 2) * 64 + l], svc);
        wv3 = dec8(wi0[(g0 + 3) * 64 + l], svc);
      }
#pragma unroll
      for (int j = 0; j < 4; ++j) {
        const f4 wf = (j == 0) ? wv0 : (j == 1) ? wv1 : (j == 2) ? wv2 : wv3;
        const int cc = qq * 4 + j;
#pragma unroll
        for (int r = 0; r < 16; ++r) {
          const f4 xv = xt4[r * 16 + (cc ^ (r & 7))];   // all-lane broadcast
          float a = acc[r];
          a = __fmaf_rn(xv.x, wf.x, a);
          a = __fmaf_rn(xv.y, wf.y, a);
          a = __fmaf_rn(xv.z, wf.z, a);
          a = __fmaf_rn(xv.w, wf.w, a);
          acc[r] = a;
        }
      }
    }

    if ((t % 6) == 5) {   // KC=384 boundary: sequential fp32 block-sum combine
#pragma unroll
      for (int r = 0; r < 16; ++r) { hs[r] = __fadd_rn(hs[r], acc[r]); acc[r] = 0.f; }
    }
  }

  // ---- layer-0 epilogue: BN + 4-bit act -> a1 [16][64] (per-lane channel scalars) ----
  {
    const float g = wsf[F_BN0 + l], be = wsf[F_BN0 + 64 + l];
    const float m = wsf[F_BN0 + 128 + l], rr = wsf[F_BN0 + 192 + l];
#pragma unroll
    for (int r = 0; r < 16; ++r)
      xa1[r * 64 + l] = bn_act4(hs[r], g, be, m, rr);
  }

  // ---- layer 1: a1 -> a2 ----
  {
    const f4* wq1 = (const f4*)(wsf + F_WQ1);
    const f4* a14 = (const f4*)xa1;
    float a1c[16];
#pragma unroll
    for (int r = 0; r < 16; ++r) a1c[r] = 0.f;
#pragma unroll
    for (int cc = 0; cc < 16; ++cc) {
      const f4 wf = wq1[cc * 64 + l];
#pragma unroll
      for (int r = 0; r < 16; ++r) {
        const f4 xv = a14[r * 16 + cc];
        float a = a1c[r];
        a = __fmaf_rn(xv.x, wf.x, a);
        a = __fmaf_rn(xv.y, wf.y, a);
        a = __fmaf_rn(xv.z, wf.z, a);
        a = __fmaf_rn(xv.w, wf.w, a);
        a1c[r] = a;
      }
    }
    const float g = wsf[F_BN1 + l], be = wsf[F_BN1 + 64 + l];
    const float m = wsf[F_BN1 + 128 + l], rr = wsf[F_BN1 + 192 + l];
#pragma unroll
    for (int r = 0; r < 16; ++r)
      a2[r * 64 + l] = bn_act4(a1c[r], g, be, m, rr);
  }

  // ---- layer 2: a2 -> a1 ----
  {
    const f4* wq2 = (const f4*)(wsf + F_WQ2);
    const f4* a24 = (const f4*)a2;
    float a2c[16];
#pragma unroll
    for (int r = 0; r < 16; ++r) a2c[r] = 0.f;
#pragma unroll
    for (int cc = 0; cc < 16; ++cc) {
      const f4 wf = wq2[cc * 64 + l];
#pragma unroll
      for (int r = 0; r < 16; ++r) {
        const f4 xv = a24[r * 16 + cc];
        float a = a2c[r];
        a = __fmaf_rn(xv.x, wf.x, a);
        a = __fmaf_rn(xv.y, wf.y, a);
        a = __fmaf_rn(xv.z, wf.z, a);
        a = __fmaf_rn(xv.w, wf.w, a);
        a2c[r] = a;
      }
    }
    const float g = wsf[F_BN2 + l], be = wsf[F_BN2 + 64 + l];
    const float m = wsf[F_BN2 + 128 + l], rr = wsf[F_BN2 + 192 + l];
#pragma unroll
    for (int r = 0; r < 16; ++r)
      xa1[r * 64 + l] = bn_act4(a2c[r], g, be, m, rr);
  }

  // ---- layer 3: 10 outputs, BN affine, no act ----
  {
    const f4* wq3 = (const f4*)(wsf + F_WQ3);
    const f4* a14 = (const f4*)xa1;
    float a3c[16];
#pragma unroll
    for (int r = 0; r < 16; ++r) a3c[r] = 0.f;
#pragma unroll
    for (int cc = 0; cc < 16; ++cc) {
      const f4 wf = wq3[cc * 64 + l];
#pragma unroll
      for (int r = 0; r < 16; ++r) {
        const f4 xv = a14[r * 16 + cc];
        float a = a3c[r];
        a = __fmaf_rn(xv.x, wf.x, a);
        a = __fmaf_rn(xv.y, wf.y, a);
        a = __fmaf_rn(xv.z, wf.z, a);
        a = __fmaf_rn(xv.w, wf.w, a);
        a3c[r] = a;
      }
    }
    if (l < 10) {
      const float g = wsf[F_BN3 + l], be = wsf[F_BN3 + 16 + l];
      const float m = wsf[F_BN3 + 32 + l], rr = wsf[F_BN3 + 48 + l];
#pragma unroll
      for (int r = 0; r < 16; ++r) {
        const float o = __fadd_rn(__fmul_rn(__fmul_rn(g, __fsub_rn(a3c[r], m)), rr), be);
        out[(long)(row0 + r) * 10 + l] = o;
      }
    }
  }
}

extern "C" void kernel_launch(void* const* d_in, const int* in_sizes, int n_in,
                              void* d_out, int out_size, void* d_ws, size_t ws_size,
                              hipStream_t stream) {
  (void)in_sizes; (void)n_in; (void)out_size;
  InPtrs P;
  for (int i = 0; i < 25; ++i) P.p[i] = (const float*)d_in[i];
  float* wsf = (float*)d_ws;
  const int wf32 = (ws_size >= WS_NEED_F32) ? 1 : 0;
  qtfc_prep<<<193, 256, 0, stream>>>(P, wsf, wf32);
  if (wf32)
    qtfc_main<0><<<512, 256, 0, stream>>>((const float*)d_in[0], wsf, (float*)d_out);
  else
    qtfc_main<1><<<512, 256, 0, stream>>>((const float*)d_in[0], wsf, (float*)d_out);
}